// Round 3
// baseline (197.851 us; speedup 1.0000x reference)
//
#include <hip/hip_runtime.h>
#include <hip/hip_cooperative_groups.h>
#include <math.h>

namespace cg = cooperative_groups;

// (B,N,F) = (8, 4096, 256), fp32 in/out. out = (B, 5, F).
constexpr int B = 8;
constexpr int N = 4096;
constexpr int F = 256;
constexpr int F4 = F / 4;          // 64 float4 per row
constexpr int CHUNKS = 64;         // blocks per batch
constexpr int RPC = N / CHUNKS;    // 64 rows per chunk

__global__ void __launch_bounds__(256)
fused_kernel(const float* __restrict__ ref_rgb, const float* __restrict__ ref_flow,
             const float* __restrict__ sup_rgb, const float* __restrict__ sup_flow,
             float* __restrict__ out,
             float* __restrict__ partial,
             float* __restrict__ cand_val, int* __restrict__ cand_idx,
             float* __restrict__ cand2_val, int* __restrict__ cand2_idx) {
    cg::grid_group grid = cg::this_grid();
    const int b = blockIdx.x, chunk = blockIdx.y;
    const int t = threadIdx.x;          // 256 threads
    const int wave = t >> 6, lane = t & 63;

    __shared__ float4 red[4][64];
    __shared__ float  S[F];
    __shared__ float  score[RPC];
    __shared__ float  sval[256];
    __shared__ int    sgid[256];
    __shared__ float  cval[256];
    __shared__ int    cgid[256];
    __shared__ int    chosen[3];
    __shared__ float  Tv[F];

    // ================= Phase A: partial column sum of my 64 ref_flow rows =================
    {
        const float4* base = reinterpret_cast<const float4*>(ref_flow)
                           + ((size_t)b * N + (size_t)chunk * RPC) * F4;
        float4 acc = make_float4(0.f, 0.f, 0.f, 0.f);
        for (int r = wave; r < RPC; r += 4) {
            float4 v = base[(size_t)r * F4 + lane];
            acc.x += v.x; acc.y += v.y; acc.z += v.z; acc.w += v.w;
        }
        red[wave][lane] = acc;
        __syncthreads();
        if (wave == 0) {
            float4 a0 = red[0][lane], a1 = red[1][lane], a2 = red[2][lane], a3 = red[3][lane];
            float4 s = make_float4(a0.x + a1.x + a2.x + a3.x,
                                   a0.y + a1.y + a2.y + a3.y,
                                   a0.z + a1.z + a2.z + a3.z,
                                   a0.w + a1.w + a2.w + a3.w);
            reinterpret_cast<float4*>(partial)[((size_t)b * CHUNKS + chunk) * F4 + lane] = s;
        }
    }
    grid.sync();

    // ============ Phase B: S = sum of partials (redundant), dot my rows, local top-3 min ============
    {
        float acc = 0.f;
        #pragma unroll 8
        for (int p = 0; p < CHUNKS; ++p) acc += partial[((size_t)b * CHUNKS + p) * F + t];
        S[t] = acc;
        __syncthreads();

        float4 s4 = reinterpret_cast<const float4*>(S)[lane];
        const float4* rowbase = reinterpret_cast<const float4*>(ref_flow)
                              + ((size_t)b * N + (size_t)chunk * RPC) * F4;
        for (int r = wave; r < RPC; r += 4) {
            float4 a = rowbase[(size_t)r * F4 + lane];
            float d = a.x * s4.x + a.y * s4.y + a.z * s4.z + a.w * s4.w;
            #pragma unroll
            for (int off = 32; off; off >>= 1) d += __shfl_down(d, off);
            if (lane == 0) score[r] = d;
        }
        __syncthreads();

        for (int k = 0; k < 3; ++k) {
            if (t < RPC) { sval[t] = score[t]; sgid[t] = t; }
            __syncthreads();
            for (int s = RPC / 2; s; s >>= 1) {
                if (t < s) {
                    float ov = sval[t + s]; int oi = sgid[t + s];
                    if (ov < sval[t] || (ov == sval[t] && oi < sgid[t])) { sval[t] = ov; sgid[t] = oi; }
                }
                __syncthreads();
            }
            if (t == 0) {
                cand_val[(b * CHUNKS + chunk) * 3 + k] = sval[0];
                cand_idx[(b * CHUNKS + chunk) * 3 + k] = chunk * RPC + sgid[0];
                score[sgid[0]] = INFINITY;
            }
            __syncthreads();
        }
    }
    grid.sync();

    // ===== Phase C: merge 192 candidates (redundant) -> top-3, build Tv, write out rows 0..2,
    //               dot sup rows, local top-2 max =====
    {
        constexpr int NC = 3 * CHUNKS;  // 192
        cval[t] = (t < NC) ? cand_val[b * NC + t] : INFINITY;
        cgid[t] = (t < NC) ? cand_idx[b * NC + t] : 0x7fffffff;
        __syncthreads();

        for (int k = 0; k < 3; ++k) {
            sval[t] = cval[t]; sgid[t] = cgid[t];
            __syncthreads();
            for (int s = 128; s; s >>= 1) {
                if (t < s) {
                    float ov = sval[t + s]; int oi = sgid[t + s];
                    if (ov < sval[t] || (ov == sval[t] && oi < sgid[t])) { sval[t] = ov; sgid[t] = oi; }
                }
                __syncthreads();
            }
            if (t == 0) chosen[k] = sgid[0];
            __syncthreads();
            if (cgid[t] == chosen[k]) cval[t] = INFINITY;
            __syncthreads();
        }

        const int i0 = chosen[0], i1 = chosen[1], i2 = chosen[2];
        Tv[t] = ref_flow[((size_t)b * N + i0) * F + t]
              + ref_flow[((size_t)b * N + i1) * F + t]
              + ref_flow[((size_t)b * N + i2) * F + t];
        if (chunk == 0) {
            out[((size_t)b * 5 + 0) * F + t] = ref_rgb[((size_t)b * N + i0) * F + t];
            out[((size_t)b * 5 + 1) * F + t] = ref_rgb[((size_t)b * N + i1) * F + t];
            out[((size_t)b * 5 + 2) * F + t] = ref_rgb[((size_t)b * N + i2) * F + t];
        }
        __syncthreads();

        float4 s4 = reinterpret_cast<const float4*>(Tv)[lane];
        const float4* rowbase = reinterpret_cast<const float4*>(sup_flow)
                              + ((size_t)b * N + (size_t)chunk * RPC) * F4;
        for (int r = wave; r < RPC; r += 4) {
            float4 a = rowbase[(size_t)r * F4 + lane];
            float d = a.x * s4.x + a.y * s4.y + a.z * s4.z + a.w * s4.w;
            #pragma unroll
            for (int off = 32; off; off >>= 1) d += __shfl_down(d, off);
            if (lane == 0) score[r] = d;
        }
        __syncthreads();

        for (int k = 0; k < 2; ++k) {
            if (t < RPC) { sval[t] = score[t]; sgid[t] = t; }
            __syncthreads();
            for (int s = RPC / 2; s; s >>= 1) {
                if (t < s) {
                    float ov = sval[t + s]; int oi = sgid[t + s];
                    if (ov > sval[t] || (ov == sval[t] && oi < sgid[t])) { sval[t] = ov; sgid[t] = oi; }
                }
                __syncthreads();
            }
            if (t == 0) {
                cand2_val[(b * CHUNKS + chunk) * 2 + k] = sval[0];
                cand2_idx[(b * CHUNKS + chunk) * 2 + k] = chunk * RPC + sgid[0];
                score[sgid[0]] = -INFINITY;
            }
            __syncthreads();
        }
    }
    grid.sync();

    // ============== Phase D: one block per batch merges 128 cand2 -> rows 3..4 ==============
    if (chunk == 0) {
        constexpr int NC2 = 2 * CHUNKS;  // 128
        if (t < NC2) { cval[t] = cand2_val[b * NC2 + t]; cgid[t] = cand2_idx[b * NC2 + t]; }
        __syncthreads();

        for (int k = 0; k < 2; ++k) {
            if (t < NC2) { sval[t] = cval[t]; sgid[t] = cgid[t]; }
            __syncthreads();
            for (int s = NC2 / 2; s; s >>= 1) {
                if (t < s) {
                    float ov = sval[t + s]; int oi = sgid[t + s];
                    if (ov > sval[t] || (ov == sval[t] && oi < sgid[t])) { sval[t] = ov; sgid[t] = oi; }
                }
                __syncthreads();
            }
            if (t == 0) chosen[k] = sgid[0];
            __syncthreads();
            if (t < NC2 && cgid[t] == chosen[k]) cval[t] = -INFINITY;
            __syncthreads();
        }

        out[((size_t)b * 5 + 3) * F + t] = sup_rgb[((size_t)b * N + chosen[0]) * F + t];
        out[((size_t)b * 5 + 4) * F + t] = sup_rgb[((size_t)b * N + chosen[1]) * F + t];
    }
}

extern "C" void kernel_launch(void* const* d_in, const int* in_sizes, int n_in,
                              void* d_out, int out_size, void* d_ws, size_t ws_size,
                              hipStream_t stream) {
    const float* ref_rgb  = (const float*)d_in[0];
    const float* ref_flow = (const float*)d_in[1];
    const float* sup_rgb  = (const float*)d_in[2];
    const float* sup_flow = (const float*)d_in[3];
    float* out = (float*)d_out;

    float* ws        = (float*)d_ws;
    float* partial   = ws;                                      // B*CHUNKS*F = 131072
    float* cand_val  = partial + (size_t)B * CHUNKS * F;        // B*CHUNKS*3
    float* cand2_val = cand_val + (size_t)B * CHUNKS * 3;       // B*CHUNKS*2
    int*   cand_idx  = (int*)(cand2_val + (size_t)B * CHUNKS * 2);
    int*   cand2_idx = cand_idx + (size_t)B * CHUNKS * 3;

    void* args[] = { (void*)&ref_rgb, (void*)&ref_flow, (void*)&sup_rgb, (void*)&sup_flow,
                     (void*)&out, (void*)&partial, (void*)&cand_val, (void*)&cand_idx,
                     (void*)&cand2_val, (void*)&cand2_idx };
    hipLaunchCooperativeKernel((const void*)fused_kernel, dim3(B, CHUNKS), dim3(256),
                               args, 0, stream);
}

// Round 4
// 171.161 us; speedup vs baseline: 1.1559x; 1.1559x over previous
//
#include <hip/hip_runtime.h>

// (B,N,F) = (8, 4096, 256), fp32 in/out. out = (B, 5, F).
constexpr int B = 8;
constexpr int N = 4096;
constexpr int F = 256;
constexpr int F4 = F / 4;        // 64 float4 per row
constexpr int CHUNKS = 64;       // blocks per batch
constexpr int RPC = N / CHUNKS;  // 64 rows per block

// Monotone float->uint mapping: f<g  <=>  sortable(f)<sortable(g)
__device__ __forceinline__ unsigned sortable_f32(float f) {
    unsigned u = __float_as_uint(f);
    return (u & 0x80000000u) ? ~u : (u | 0x80000000u);
}

// Per-batch barrier over CHUNKS blocks. All threads call; t0 arrives+spins.
// Safe: grid=512 blocks, 2 blocks/CU guaranteed resident (LDS+launch_bounds) => all co-resident.
__device__ __forceinline__ void batch_barrier(int* c) {
    __threadfence();          // release this thread's global writes
    __syncthreads();          // all block's writes ordered before t0's arrive
    if (threadIdx.x == 0) {
        atomicAdd(c, 1);
        while (__hip_atomic_load(c, __ATOMIC_RELAXED, __HIP_MEMORY_SCOPE_AGENT) < CHUNKS)
            __builtin_amdgcn_s_sleep(4);
        __threadfence();      // acquire: invalidate stale cache lines
    }
    __syncthreads();
}

__global__ void __launch_bounds__(256, 2)
fused(const float* __restrict__ ref_rgb, const float* __restrict__ ref_flow,
      const float* __restrict__ sup_rgb, const float* __restrict__ sup_flow,
      float* __restrict__ out, int* __restrict__ cntbase,
      unsigned long long* __restrict__ minbase, unsigned long long* __restrict__ maxbase,
      float* __restrict__ partial) {
    const int b = blockIdx.x, chunk = blockIdx.y;
    const int t = threadIdx.x;           // 256 threads
    const int wave = t >> 6, lane = t & 63;

    __shared__ float4 rows[RPC][F4];     // 64 KB: my ref_flow rows (phase A -> B)
    __shared__ float4 red[4][F4];        // 4 KB
    __shared__ float  S[F];
    __shared__ float  Tv[F];
    __shared__ float  scoreS[RPC];
    __shared__ int    chosen[3];
    __shared__ int    lastFlag;

    int* cnt0 = cntbase + (0 * B + b) * 32;   // 128B-strided counters (no false sharing)
    int* cnt1 = cntbase + (1 * B + b) * 32;
    int* cnt2 = cntbase + (2 * B + b) * 32;
    unsigned long long* minslot = minbase + (size_t)b * 16;  // 3 slots used, memset 0 (stores ~packed)
    unsigned long long* maxslot = maxbase + (size_t)b * 16;  // 2 slots used, memset 0

    // ---------------- Phase A: stage my ref rows in LDS + column partial sums ----------------
    const float4* rbase = reinterpret_cast<const float4*>(ref_flow)
                        + ((size_t)b * N + (size_t)chunk * RPC) * F4;
    float4 acc = make_float4(0.f, 0.f, 0.f, 0.f);
    #pragma unroll
    for (int i = 0; i < RPC / 4; ++i) {
        const int r = wave + 4 * i;
        float4 v = rbase[(size_t)r * F4 + lane];
        rows[r][lane] = v;
        acc.x += v.x; acc.y += v.y; acc.z += v.z; acc.w += v.w;
    }

    // Prefetch my sup_flow rows into registers (consumed in phase C; HBM latency hides
    // under phases A/B and both barrier waits). Static indexing -> stays in VGPRs.
    const float4* sbase = reinterpret_cast<const float4*>(sup_flow)
                        + ((size_t)b * N + (size_t)chunk * RPC) * F4;
    float4 supreg[RPC / 4];
    #pragma unroll
    for (int i = 0; i < RPC / 4; ++i)
        supreg[i] = sbase[(size_t)(wave + 4 * i) * F4 + lane];

    red[wave][lane] = acc;
    __syncthreads();
    if (wave == 0) {
        float4 a0 = red[0][lane], a1 = red[1][lane], a2 = red[2][lane], a3 = red[3][lane];
        float4 s = make_float4(a0.x + a1.x + a2.x + a3.x, a0.y + a1.y + a2.y + a3.y,
                               a0.z + a1.z + a2.z + a3.z, a0.w + a1.w + a2.w + a3.w);
        reinterpret_cast<float4*>(partial)[((size_t)b * CHUNKS + chunk) * F4 + lane] = s;
    }

    batch_barrier(cnt0);

    // ---------------- Phase B: S = sum partials (redundant), dots from LDS, local top-3 min ----------------
    {
        float sacc = 0.f;
        #pragma unroll 8
        for (int p = 0; p < CHUNKS; ++p) sacc += partial[((size_t)b * CHUNKS + p) * F + t];
        S[t] = sacc;
        __syncthreads();

        float4 s4 = reinterpret_cast<const float4*>(S)[lane];
        #pragma unroll
        for (int i = 0; i < RPC / 4; ++i) {
            const int r = wave + 4 * i;
            float4 a = rows[r][lane];
            float d = a.x * s4.x + a.y * s4.y + a.z * s4.z + a.w * s4.w;
            #pragma unroll
            for (int off = 32; off; off >>= 1) d += __shfl_xor(d, off);
            if (lane == 0) scoreS[r] = d;
        }
        __syncthreads();

        if (wave == 0) {
            // inv = ~packed: larger inv == smaller (score, idx). Unique per lane.
            const unsigned gidx = (unsigned)(chunk * RPC + lane);
            unsigned long long inv =
                ~((((unsigned long long)sortable_f32(scoreS[lane])) << 32) | (unsigned long long)gidx);
            unsigned long long cur = inv;
            for (int k = 0; k < 3; ++k) {
                unsigned long long m = cur;
                #pragma unroll
                for (int off = 32; off; off >>= 1) {
                    unsigned long long o = __shfl_xor(m, off);
                    if (o > m) m = o;
                }
                if (lane == 0) {
                    // lock-free bubbling insert: slots end as exact top-3 (sorted desc in inv)
                    unsigned long long x = m;
                    #pragma unroll
                    for (int s = 0; s < 3; ++s) {
                        unsigned long long old = atomicMax(&minslot[s], x);
                        x = (old < x) ? old : x;
                    }
                }
                if (cur == m) cur = 0;  // exclude found element (0 = worst)
            }
        }
    }

    batch_barrier(cnt1);

    // ---------------- Phase C: decode top-3, Tv, rows 0-2, sup dots (regs), local top-2 max ----------------
    if (t == 0) {
        unsigned long long y0 = __hip_atomic_load(&minslot[0], __ATOMIC_RELAXED, __HIP_MEMORY_SCOPE_AGENT);
        unsigned long long y1 = __hip_atomic_load(&minslot[1], __ATOMIC_RELAXED, __HIP_MEMORY_SCOPE_AGENT);
        unsigned long long y2 = __hip_atomic_load(&minslot[2], __ATOMIC_RELAXED, __HIP_MEMORY_SCOPE_AGENT);
        // sort desc in inv == ascending (score, idx): best first (matches jax order)
        unsigned long long tmp;
        if (y1 > y0) { tmp = y0; y0 = y1; y1 = tmp; }
        if (y2 > y0) { tmp = y0; y0 = y2; y2 = tmp; }
        if (y2 > y1) { tmp = y1; y1 = y2; y2 = tmp; }
        chosen[0] = (int)((~y0) & 0xFFFFFFFFull);
        chosen[1] = (int)((~y1) & 0xFFFFFFFFull);
        chosen[2] = (int)((~y2) & 0xFFFFFFFFull);
    }
    __syncthreads();
    {
        const int i0 = chosen[0], i1 = chosen[1], i2 = chosen[2];
        Tv[t] = ref_flow[((size_t)b * N + i0) * F + t]
              + ref_flow[((size_t)b * N + i1) * F + t]
              + ref_flow[((size_t)b * N + i2) * F + t];
        if (chunk == 0) {
            out[((size_t)b * 5 + 0) * F + t] = ref_rgb[((size_t)b * N + i0) * F + t];
            out[((size_t)b * 5 + 1) * F + t] = ref_rgb[((size_t)b * N + i1) * F + t];
            out[((size_t)b * 5 + 2) * F + t] = ref_rgb[((size_t)b * N + i2) * F + t];
        }
    }
    __syncthreads();
    {
        float4 tv4 = reinterpret_cast<const float4*>(Tv)[lane];
        #pragma unroll
        for (int i = 0; i < RPC / 4; ++i) {
            const int r = wave + 4 * i;
            float4 a = supreg[i];
            float d = a.x * tv4.x + a.y * tv4.y + a.z * tv4.z + a.w * tv4.w;
            #pragma unroll
            for (int off = 32; off; off >>= 1) d += __shfl_xor(d, off);
            if (lane == 0) scoreS[r] = d;
        }
        __syncthreads();

        if (wave == 0) {
            // packed: larger == larger score, tie -> smaller index wins max
            const unsigned gidx = (unsigned)(chunk * RPC + lane);
            unsigned long long pk =
                (((unsigned long long)sortable_f32(scoreS[lane])) << 32) |
                (unsigned long long)(0xFFFFFFFFu - gidx);
            unsigned long long cur = pk;
            for (int k = 0; k < 2; ++k) {
                unsigned long long m = cur;
                #pragma unroll
                for (int off = 32; off; off >>= 1) {
                    unsigned long long o = __shfl_xor(m, off);
                    if (o > m) m = o;
                }
                if (lane == 0) {
                    unsigned long long x = m;
                    #pragma unroll
                    for (int s = 0; s < 2; ++s) {
                        unsigned long long old = atomicMax(&maxslot[s], x);
                        x = (old < x) ? old : x;
                    }
                }
                if (cur == m) cur = 0;
            }
        }
    }

    // ---------------- Phase D: last arriver per batch merges + gathers rows 3-4 (no spin) ----------------
    __threadfence();
    __syncthreads();
    if (t == 0) {
        int old = atomicAdd(cnt2, 1);
        lastFlag = (old == CHUNKS - 1);
    }
    __syncthreads();
    if (lastFlag) {
        if (t == 0) {
            __threadfence();
            unsigned long long y0 = __hip_atomic_load(&maxslot[0], __ATOMIC_RELAXED, __HIP_MEMORY_SCOPE_AGENT);
            unsigned long long y1 = __hip_atomic_load(&maxslot[1], __ATOMIC_RELAXED, __HIP_MEMORY_SCOPE_AGENT);
            if (y1 > y0) { unsigned long long tmp = y0; y0 = y1; y1 = tmp; }
            chosen[0] = (int)(0xFFFFFFFFu - (unsigned)(y0 & 0xFFFFFFFFull));
            chosen[1] = (int)(0xFFFFFFFFu - (unsigned)(y1 & 0xFFFFFFFFull));
        }
        __syncthreads();
        out[((size_t)b * 5 + 3) * F + t] = sup_rgb[((size_t)b * N + chosen[0]) * F + t];
        out[((size_t)b * 5 + 4) * F + t] = sup_rgb[((size_t)b * N + chosen[1]) * F + t];
    }
}

extern "C" void kernel_launch(void* const* d_in, const int* in_sizes, int n_in,
                              void* d_out, int out_size, void* d_ws, size_t ws_size,
                              hipStream_t stream) {
    const float* ref_rgb  = (const float*)d_in[0];
    const float* ref_flow = (const float*)d_in[1];
    const float* sup_rgb  = (const float*)d_in[2];
    const float* sup_flow = (const float*)d_in[3];
    float* out = (float*)d_out;

    // ws layout: [0,3072) counters (3 phases x 8 batches x 128B stride)
    //            [4096,5120) minslots   [8192,9216) maxslots   [16384,...) partial (2 MB)
    int* cntbase = (int*)d_ws;
    unsigned long long* minbase = (unsigned long long*)((char*)d_ws + 4096);
    unsigned long long* maxbase = (unsigned long long*)((char*)d_ws + 8192);
    float* partial = (float*)((char*)d_ws + 16384);

    hipMemsetAsync(d_ws, 0, 16384, stream);  // re-init sync state every call (replay-safe)
    fused<<<dim3(B, CHUNKS), 256, 0, stream>>>(ref_rgb, ref_flow, sup_rgb, sup_flow,
                                               out, cntbase, minbase, maxbase, partial);
}

// Round 5
// 53.479 us; speedup vs baseline: 3.6996x; 3.2005x over previous
//
#include <hip/hip_runtime.h>

// (B,N,F) = (8, 4096, 256), fp32 in/out. out = (B, 5, F).
constexpr int B = 8;
constexpr int N = 4096;
constexpr int F = 256;
constexpr int F4 = F / 4;        // 64 float4 per row
constexpr int CHUNKS = 64;       // blocks per batch
constexpr int RPC = N / CHUNKS;  // 64 rows per block

// Monotone float->uint mapping: f<g  <=>  sortable(f)<sortable(g)
__device__ __forceinline__ unsigned sortable_f32(float f) {
    unsigned u = __float_as_uint(f);
    return (u & 0x80000000u) ? ~u : (u | 0x80000000u);
}

// Per-batch fence-FREE barrier. Producer ordering: each wave's sc1 (agent-scope)
// stores are acked at the coherence point before vmcnt(0) clears; __syncthreads
// covers all waves; then t0 bumps the counter. Readers poll the counter and read
// the data with agent-scope loads (bypass stale caches) — no buffer_wbl2/inv ever.
// Co-residency: grid = 512 blocks <= 2/CU * 256 CU (LDS ~6KB, VGPR ~110) => no deadlock.
__device__ __forceinline__ void fencefree_barrier(int* c) {
    asm volatile("s_waitcnt vmcnt(0)" ::: "memory");
    __syncthreads();
    if (threadIdx.x == 0) {
        __hip_atomic_fetch_add(c, 1, __ATOMIC_RELAXED, __HIP_MEMORY_SCOPE_AGENT);
        while (__hip_atomic_load(c, __ATOMIC_RELAXED, __HIP_MEMORY_SCOPE_AGENT) < CHUNKS)
            __builtin_amdgcn_s_sleep(8);
    }
    __syncthreads();
}

__global__ void __launch_bounds__(256, 2)
fused(const float* __restrict__ ref_rgb, const float* __restrict__ ref_flow,
      const float* __restrict__ sup_rgb, const float* __restrict__ sup_flow,
      float* __restrict__ out, int* __restrict__ cntbase,
      unsigned long long* __restrict__ minbase, unsigned long long* __restrict__ maxbase,
      float* __restrict__ partial) {
    const int b = blockIdx.x, chunk = blockIdx.y;
    const int t = threadIdx.x;           // 256 threads
    const int wave = t >> 6, lane = t & 63;

    __shared__ float4 red[4][F4];        // 4 KB
    __shared__ float  S[F];
    __shared__ float  Tv[F];
    __shared__ float  scoreS[RPC];
    __shared__ int    chosen[3];
    __shared__ int    lastFlag;

    int* cnt0 = cntbase + (0 * B + b) * 32;   // 128B-strided counters
    int* cnt1 = cntbase + (1 * B + b) * 32;
    int* cnt2 = cntbase + (2 * B + b) * 32;
    unsigned long long* minslot = minbase + (size_t)b * 16;  // 3 slots, memset 0 (~packed)
    unsigned long long* maxslot = maxbase + (size_t)b * 16;  // 2 slots, memset 0

    // ---------------- Phase A: column partial sums of my 64 ref_flow rows ----------------
    const float4* rbase = reinterpret_cast<const float4*>(ref_flow)
                        + ((size_t)b * N + (size_t)chunk * RPC) * F4;
    float4 acc = make_float4(0.f, 0.f, 0.f, 0.f);
    #pragma unroll
    for (int i = 0; i < RPC / 4; ++i) {
        float4 v = rbase[(size_t)(wave + 4 * i) * F4 + lane];
        acc.x += v.x; acc.y += v.y; acc.z += v.z; acc.w += v.w;
    }

    // Prefetch my sup_flow rows into registers (consumed in phase C; cold HBM read
    // hides under phases A/B and the barrier waits). Static indexing -> VGPRs.
    const float4* sbase = reinterpret_cast<const float4*>(sup_flow)
                        + ((size_t)b * N + (size_t)chunk * RPC) * F4;
    float4 supreg[RPC / 4];
    #pragma unroll
    for (int i = 0; i < RPC / 4; ++i)
        supreg[i] = sbase[(size_t)(wave + 4 * i) * F4 + lane];

    red[wave][lane] = acc;
    __syncthreads();
    if (wave == 0) {
        float4 a0 = red[0][lane], a1 = red[1][lane], a2 = red[2][lane], a3 = red[3][lane];
        float4 s = make_float4(a0.x + a1.x + a2.x + a3.x, a0.y + a1.y + a2.y + a3.y,
                               a0.z + a1.z + a2.z + a3.z, a0.w + a1.w + a2.w + a3.w);
        // agent-scope (sc1, write-through) stores: visible device-wide once vmcnt acks
        float* pdst = partial + ((size_t)b * CHUNKS + chunk) * F + 4 * lane;
        __hip_atomic_store(pdst + 0, s.x, __ATOMIC_RELAXED, __HIP_MEMORY_SCOPE_AGENT);
        __hip_atomic_store(pdst + 1, s.y, __ATOMIC_RELAXED, __HIP_MEMORY_SCOPE_AGENT);
        __hip_atomic_store(pdst + 2, s.z, __ATOMIC_RELAXED, __HIP_MEMORY_SCOPE_AGENT);
        __hip_atomic_store(pdst + 3, s.w, __ATOMIC_RELAXED, __HIP_MEMORY_SCOPE_AGENT);
    }

    fencefree_barrier(cnt0);

    // ---------- Phase B: S = sum partials (redundant, coherent loads), dots, local top-3 min ----------
    {
        float sacc = 0.f;
        float* pbase = partial + (size_t)b * CHUNKS * F + t;
        #pragma unroll 8
        for (int p = 0; p < CHUNKS; ++p)
            sacc += __hip_atomic_load(pbase + (size_t)p * F, __ATOMIC_RELAXED, __HIP_MEMORY_SCOPE_AGENT);
        S[t] = sacc;
        __syncthreads();

        float4 s4 = reinterpret_cast<const float4*>(S)[lane];
        #pragma unroll
        for (int i = 0; i < RPC / 4; ++i) {
            const int r = wave + 4 * i;
            float4 a = rbase[(size_t)r * F4 + lane];   // re-read: own-XCD L2 hit
            float d = a.x * s4.x + a.y * s4.y + a.z * s4.z + a.w * s4.w;
            #pragma unroll
            for (int off = 32; off; off >>= 1) d += __shfl_xor(d, off);
            if (lane == 0) scoreS[r] = d;
        }
        __syncthreads();

        if (wave == 0) {
            // inv = ~packed: larger inv == smaller (score, idx). Unique per lane.
            const unsigned gidx = (unsigned)(chunk * RPC + lane);
            unsigned long long inv =
                ~((((unsigned long long)sortable_f32(scoreS[lane])) << 32) | (unsigned long long)gidx);
            unsigned long long cur = inv;
            for (int k = 0; k < 3; ++k) {
                unsigned long long m = cur;
                #pragma unroll
                for (int off = 32; off; off >>= 1) {
                    unsigned long long o = __shfl_xor(m, off);
                    if (o > m) m = o;
                }
                if (lane == 0) {
                    unsigned long long x = m;   // lock-free bubbling insert (exact top-3)
                    #pragma unroll
                    for (int s = 0; s < 3; ++s) {
                        unsigned long long old = atomicMax(&minslot[s], x);
                        x = (old < x) ? old : x;
                    }
                }
                if (cur == m) cur = 0;
            }
        }
    }

    fencefree_barrier(cnt1);

    // ------- Phase C: decode top-3, Tv, rows 0-2, sup dots (regs), local top-2 max -------
    if (t == 0) {
        unsigned long long y0 = __hip_atomic_load(&minslot[0], __ATOMIC_RELAXED, __HIP_MEMORY_SCOPE_AGENT);
        unsigned long long y1 = __hip_atomic_load(&minslot[1], __ATOMIC_RELAXED, __HIP_MEMORY_SCOPE_AGENT);
        unsigned long long y2 = __hip_atomic_load(&minslot[2], __ATOMIC_RELAXED, __HIP_MEMORY_SCOPE_AGENT);
        unsigned long long tmp;
        if (y1 > y0) { tmp = y0; y0 = y1; y1 = tmp; }
        if (y2 > y0) { tmp = y0; y0 = y2; y2 = tmp; }
        if (y2 > y1) { tmp = y1; y1 = y2; y2 = tmp; }
        chosen[0] = (int)((~y0) & 0xFFFFFFFFull);
        chosen[1] = (int)((~y1) & 0xFFFFFFFFull);
        chosen[2] = (int)((~y2) & 0xFFFFFFFFull);
    }
    __syncthreads();
    {
        const int i0 = chosen[0], i1 = chosen[1], i2 = chosen[2];
        Tv[t] = ref_flow[((size_t)b * N + i0) * F + t]      // input data: read-only, cache-safe
              + ref_flow[((size_t)b * N + i1) * F + t]
              + ref_flow[((size_t)b * N + i2) * F + t];
        if (chunk == 0) {
            out[((size_t)b * 5 + 0) * F + t] = ref_rgb[((size_t)b * N + i0) * F + t];
            out[((size_t)b * 5 + 1) * F + t] = ref_rgb[((size_t)b * N + i1) * F + t];
            out[((size_t)b * 5 + 2) * F + t] = ref_rgb[((size_t)b * N + i2) * F + t];
        }
    }
    __syncthreads();
    {
        float4 tv4 = reinterpret_cast<const float4*>(Tv)[lane];
        #pragma unroll
        for (int i = 0; i < RPC / 4; ++i) {
            const int r = wave + 4 * i;
            float4 a = supreg[i];
            float d = a.x * tv4.x + a.y * tv4.y + a.z * tv4.z + a.w * tv4.w;
            #pragma unroll
            for (int off = 32; off; off >>= 1) d += __shfl_xor(d, off);
            if (lane == 0) scoreS[r] = d;
        }
        __syncthreads();

        if (wave == 0) {
            // packed: larger == larger score, tie -> smaller index
            const unsigned gidx = (unsigned)(chunk * RPC + lane);
            unsigned long long pk =
                (((unsigned long long)sortable_f32(scoreS[lane])) << 32) |
                (unsigned long long)(0xFFFFFFFFu - gidx);
            unsigned long long cur = pk;
            for (int k = 0; k < 2; ++k) {
                unsigned long long m = cur;
                #pragma unroll
                for (int off = 32; off; off >>= 1) {
                    unsigned long long o = __shfl_xor(m, off);
                    if (o > m) m = o;
                }
                if (lane == 0) {
                    unsigned long long x = m;
                    #pragma unroll
                    for (int s = 0; s < 2; ++s) {
                        unsigned long long old = atomicMax(&maxslot[s], x);
                        x = (old < x) ? old : x;
                    }
                }
                if (cur == m) cur = 0;
            }
        }
    }

    // -------- Phase D: last arriver per batch (no spin) merges + gathers rows 3-4 --------
    asm volatile("s_waitcnt vmcnt(0)" ::: "memory");   // my atomicMax ops are globally visible
    __syncthreads();
    if (t == 0) {
        int old = __hip_atomic_fetch_add(cnt2, 1, __ATOMIC_RELAXED, __HIP_MEMORY_SCOPE_AGENT);
        lastFlag = (old == CHUNKS - 1);
    }
    __syncthreads();
    if (lastFlag) {
        if (t == 0) {
            unsigned long long y0 = __hip_atomic_load(&maxslot[0], __ATOMIC_RELAXED, __HIP_MEMORY_SCOPE_AGENT);
            unsigned long long y1 = __hip_atomic_load(&maxslot[1], __ATOMIC_RELAXED, __HIP_MEMORY_SCOPE_AGENT);
            if (y1 > y0) { unsigned long long tmp = y0; y0 = y1; y1 = tmp; }
            chosen[0] = (int)(0xFFFFFFFFu - (unsigned)(y0 & 0xFFFFFFFFull));
            chosen[1] = (int)(0xFFFFFFFFu - (unsigned)(y1 & 0xFFFFFFFFull));
        }
        __syncthreads();
        out[((size_t)b * 5 + 3) * F + t] = sup_rgb[((size_t)b * N + chosen[0]) * F + t];
        out[((size_t)b * 5 + 4) * F + t] = sup_rgb[((size_t)b * N + chosen[1]) * F + t];
    }
}

extern "C" void kernel_launch(void* const* d_in, const int* in_sizes, int n_in,
                              void* d_out, int out_size, void* d_ws, size_t ws_size,
                              hipStream_t stream) {
    const float* ref_rgb  = (const float*)d_in[0];
    const float* ref_flow = (const float*)d_in[1];
    const float* sup_rgb  = (const float*)d_in[2];
    const float* sup_flow = (const float*)d_in[3];
    float* out = (float*)d_out;

    // ws: [0,3072) counters | [4096,5120) minslots | [8192,9216) maxslots | [16384,...) partial
    int* cntbase = (int*)d_ws;
    unsigned long long* minbase = (unsigned long long*)((char*)d_ws + 4096);
    unsigned long long* maxbase = (unsigned long long*)((char*)d_ws + 8192);
    float* partial = (float*)((char*)d_ws + 16384);

    hipMemsetAsync(d_ws, 0, 16384, stream);  // re-init sync state every call (replay-safe)
    fused<<<dim3(B, CHUNKS), 256, 0, stream>>>(ref_rgb, ref_flow, sup_rgb, sup_flow,
                                               out, cntbase, minbase, maxbase, partial);
}